// Round 1
// baseline (622.428 us; speedup 1.0000x reference)
//
#include <hip/hip_runtime.h>
#include <hip/hip_bf16.h>

// ProjectBEV: expand range-image coords (B,H,W,CK,2) into COO sparse-tensor
// index/value arrays, flattened float32 in return order:
//   [0, 6N)        presence_indices [N,6]  = [b, qx, qy, c, h, w]
//   [6N, 7N)       presence_vals    [N]    = 1
//   [7N, 21N)      position_indices [2N,7] = [b, qx, qy, c, h, w, d]
//   [21N, 23N)     position_vals    [2N]   = scaled_xy flat
// with n ordered as (B, CK, H, W) and input laid out (B, H, W, CK, 2).

#define BB 16
#define HH 64
#define WW 2048
#define CKK 3
#define NN (BB * CKK * HH * WW)   // 6,291,456  (23*NN < 2^31, int math is safe)

__global__ __launch_bounds__(256) void ProjectBEV_kernel(
    const float* __restrict__ in, float* __restrict__ out) {
    const int n = blockIdx.x * 256 + threadIdx.x;
    if (n >= NN) return;

    // n = ((b*CK + c)*H + h)*W + w
    const int w = n & (WW - 1);
    const int h = (n >> 11) & (HH - 1);        // W = 2^11
    const int bc = n >> 17;                    // W*H = 2^17
    const int c = bc % CKK;
    const int b = bc / CKK;

    // input offset: ((((b*H + h)*W + w)*CK + c) * 2
    const int in_off = ((((b * HH + h) * WW + w) * CKK) + c) * 2;
    const float2 xy = *(const float2*)(in + in_off);

    const float sx = xy.x * 2.0f + 1.0f;
    const float sy = xy.y * 2.0f + 81.0f;
    const float qx = (float)(int)sx;   // truncation == astype(int64) for positive vals
    const float qy = (float)(int)sy;
    const float fb = (float)b, fc = (float)c, fh = (float)h, fw = (float)w;

    // presence_indices [n,6] = [b, qx, qy, c, h, w]
    float2* p = (float2*)(out + 6 * n);
    p[0] = make_float2(fb, qx);
    p[1] = make_float2(qy, fc);
    p[2] = make_float2(fh, fw);

    // presence_vals
    out[6 * NN + n] = 1.0f;

    // position_indices rows 2n (d=0) and 2n+1 (d=1)
    float2* q = (float2*)(out + 7 * NN + 14 * n);
    q[0] = make_float2(fb, qx);
    q[1] = make_float2(qy, fc);
    q[2] = make_float2(fh, fw);
    q[3] = make_float2(0.0f, fb);
    q[4] = make_float2(qx, qy);
    q[5] = make_float2(fc, fh);
    q[6] = make_float2(fw, 1.0f);

    // position_vals [2n, 2n+1] = [sx, sy]
    *(float2*)(out + 21 * NN + 2 * n) = make_float2(sx, sy);
}

extern "C" void kernel_launch(void* const* d_in, const int* in_sizes, int n_in,
                              void* d_out, int out_size, void* d_ws, size_t ws_size,
                              hipStream_t stream) {
    const float* in = (const float*)d_in[0];
    float* out = (float*)d_out;
    const int blocks = (NN + 255) / 256;   // 24576
    ProjectBEV_kernel<<<blocks, 256, 0, stream>>>(in, out);
}

// Round 2
// 596.721 us; speedup vs baseline: 1.0431x; 1.0431x over previous
//
#include <hip/hip_runtime.h>
#include <hip/hip_bf16.h>

// ProjectBEV: expand range-image coords (B,H,W,CK,2) into COO sparse-tensor
// index/value arrays, flattened float32 in return order:
//   [0, 6N)        presence_indices [N,6]  = [b, qx, qy, c, h, w]
//   [6N, 7N)       presence_vals    [N]    = 1
//   [7N, 21N)      position_indices [2N,7] = [b, qx, qy, c, h, w, d]
//   [21N, 23N)     position_vals    [2N]   = scaled_xy flat
// n ordered as (B, CK, H, W); input laid out (B, H, W, CK, 2).
//
// R1 lesson: direct strided stores (24 B / 56 B lane stride) inflated L2 write
// transactions ~6x -> 622 us. Stage index rows in LDS, drain as coalesced
// float4 streams.

#define BB 16
#define HH 64
#define WW 2048
#define CKK 3
#define NN (BB * CKK * HH * WW)   // 6,291,456 ; divisible by 256

__global__ __launch_bounds__(256) void ProjectBEV_kernel(
    const float* __restrict__ in, float* __restrict__ out) {
    __shared__ float ldsP[256 * 6];    // presence_indices staging  (6 KB)
    __shared__ float ldsQ[256 * 14];   // position_indices staging (14 KB)

    const int tid = threadIdx.x;
    const int n0  = blockIdx.x * 256;
    const int n   = n0 + tid;          // NN % 256 == 0, no tail check

    // n = ((b*CK + c)*H + h)*W + w
    const int w  = n & (WW - 1);
    const int h  = (n >> 11) & (HH - 1);       // W = 2^11
    const int bc = n >> 17;                    // W*H = 2^17
    const int c  = bc % CKK;
    const int b  = bc / CKK;

    // input offset: (((b*H + h)*W + w)*CK + c) * 2
    const int in_off = ((((b * HH + h) * WW + w) * CKK) + c) * 2;
    const float2 xy = *(const float2*)(in + in_off);

    const float sx = xy.x * 2.0f + 1.0f;
    const float sy = xy.y * 2.0f + 81.0f;
    const float qx = (float)(int)sx;   // truncation == astype(int64), vals > 0
    const float qy = (float)(int)sy;
    const float fb = (float)b, fc = (float)c, fh = (float)h, fw = (float)w;

    // stage presence_indices row [b, qx, qy, c, h, w]
    float2* p = (float2*)(ldsP + 6 * tid);
    p[0] = make_float2(fb, qx);
    p[1] = make_float2(qy, fc);
    p[2] = make_float2(fh, fw);

    // stage position_indices rows 2n (d=0), 2n+1 (d=1)
    float2* q = (float2*)(ldsQ + 14 * tid);
    q[0] = make_float2(fb, qx);
    q[1] = make_float2(qy, fc);
    q[2] = make_float2(fh, fw);
    q[3] = make_float2(0.0f, fb);
    q[4] = make_float2(qx, qy);
    q[5] = make_float2(fc, fh);
    q[6] = make_float2(fw, 1.0f);

    // already-coalesced direct stores
    out[6 * NN + n] = 1.0f;                                    // presence_vals
    *(float2*)(out + 21 * NN + 2 * n) = make_float2(sx, sy);   // position_vals

    __syncthreads();

    // drain LDS as contiguous float4 streams (fully coalesced)
    const float4* srcP = (const float4*)ldsP;
    float4*       dstP = (float4*)(out + 6 * n0);              // 16B aligned: 6*n0 % 4 == 0
    #pragma unroll
    for (int i = tid; i < 384; i += 256)                       // 256*6/4
        dstP[i] = srcP[i];

    const float4* srcQ = (const float4*)ldsQ;
    float4*       dstQ = (float4*)(out + 7 * NN + 14 * n0);    // 7NN%4==0, 14*n0%4==0
    #pragma unroll
    for (int i = tid; i < 896; i += 256)                       // 256*14/4
        dstQ[i] = srcQ[i];
}

extern "C" void kernel_launch(void* const* d_in, const int* in_sizes, int n_in,
                              void* d_out, int out_size, void* d_ws, size_t ws_size,
                              hipStream_t stream) {
    const float* in = (const float*)d_in[0];
    float* out = (float*)d_out;
    ProjectBEV_kernel<<<NN / 256, 256, 0, stream>>>(in, out);
}

// Round 3
// 585.727 us; speedup vs baseline: 1.0627x; 1.0188x over previous
//
#include <hip/hip_runtime.h>
#include <hip/hip_bf16.h>

// ProjectBEV: expand range-image coords (B,H,W,CK,2) into COO sparse-tensor
// index/value arrays, flattened float32 in return order:
//   [0, 6N)        presence_indices [N,6]  = [b, qx, qy, c, h, w]
//   [6N, 7N)       presence_vals    [N]    = 1
//   [7N, 21N)      position_indices [2N,7] = [b, qx, qy, c, h, w, d]
//   [21N, 23N)     position_vals    [2N]   = scaled_xy flat
// n ordered as (B, CK, H, W); input laid out (B, H, W, CK, 2).
//
// R2 lesson: dur_us includes the harness's 2.26 GB 0xAA poison fill (~366 us)
// + input restore; kernel itself is <365 us (absent from top-5). This round:
// block = (b, h, 256-w segment) x all 3 channels, so each 24 B input group is
// fully consumed by one thread (fetch = exactly 50 MB, was ~3x), 3 items/thread,
// aliased 42 KB LDS staging (Q then P) drained as coalesced float4 streams.

#define BB 16
#define HH 64
#define WW 2048
#define CKK 3
#define NN (BB * CKK * HH * WW)   // 6,291,456
#define SEG 256                    // w's per block
#define NBLK (BB * HH * (WW / SEG))  // 8192

__global__ __launch_bounds__(256) void ProjectBEV_kernel(
    const float* __restrict__ in, float* __restrict__ out) {
    // Q staging: 3 chunks x 256 rows x 14 floats = 10752 floats (42 KB).
    // P staging (3 x 256 x 6 = 4608 floats, 18 KB) reuses the front of it.
    __shared__ float lds[CKK * SEG * 14];

    const int tid = threadIdx.x;
    const int blk = blockIdx.x;
    const int w0 = (blk & 7) * SEG;          // WW/SEG = 8
    const int h  = (blk >> 3) & (HH - 1);
    const int b  = blk >> 9;

    // ---- load this thread's full 24 B input group (all 3 channels) ----
    const float* g = in + ((b * HH + h) * WW + w0 + tid) * 6;
    const float2 v0 = ((const float2*)g)[0];   // c=0 (x,y)
    const float2 v1 = ((const float2*)g)[1];   // c=1
    const float2 v2 = ((const float2*)g)[2];   // c=2

    const float fb = (float)b, fh = (float)h, fw = (float)(w0 + tid);

    float qx[CKK], qy[CKK];
    {
        const float2 v[CKK] = {v0, v1, v2};
        #pragma unroll
        for (int c = 0; c < CKK; ++c) {
            const float sx = v[c].x * 2.0f + 1.0f;
            const float sy = v[c].y * 2.0f + 81.0f;
            qx[c] = (float)(int)sx;   // trunc == astype(int64) for positive vals
            qy[c] = (float)(int)sy;
            const int nc = ((b * CKK + c) * HH + h) * WW + w0 + tid;
            out[6 * NN + nc] = 1.0f;                                  // presence_vals
            *(float2*)(out + 21 * NN + 2 * nc) = make_float2(sx, sy); // position_vals
        }
    }

    // ---- stage position_indices rows: [b,qx,qy,c,h,w,0, b,qx,qy,c,h,w,1] ----
    #pragma unroll
    for (int c = 0; c < CKK; ++c) {
        const float fc = (float)c;
        float2* q = (float2*)(lds + (c * SEG + tid) * 14);
        q[0] = make_float2(fb, qx[c]);
        q[1] = make_float2(qy[c], fc);
        q[2] = make_float2(fh, fw);
        q[3] = make_float2(0.0f, fb);
        q[4] = make_float2(qx[c], qy[c]);
        q[5] = make_float2(fc, fh);
        q[6] = make_float2(fw, 1.0f);
    }
    __syncthreads();

    // ---- drain position_indices: 3 chunks of 896 float4, coalesced ----
    #pragma unroll
    for (int c = 0; c < CKK; ++c) {
        const int ncBase = ((b * CKK + c) * HH + h) * WW + w0;
        const float4* src = (const float4*)(lds + c * SEG * 14);
        float4* dst = (float4*)(out + 7 * NN + 14 * ncBase);  // 14*ncBase % 4 == 0
        #pragma unroll
        for (int i = tid; i < SEG * 14 / 4; i += 256)         // 896
            dst[i] = src[i];
    }
    __syncthreads();

    // ---- re-stage presence_indices rows [b,qx,qy,c,h,w] in the same LDS ----
    #pragma unroll
    for (int c = 0; c < CKK; ++c) {
        const float fc = (float)c;
        float2* p = (float2*)(lds + (c * SEG + tid) * 6);
        p[0] = make_float2(fb, qx[c]);
        p[1] = make_float2(qy[c], fc);
        p[2] = make_float2(fh, fw);
    }
    __syncthreads();

    // ---- drain presence_indices: 3 chunks of 384 float4, coalesced ----
    #pragma unroll
    for (int c = 0; c < CKK; ++c) {
        const int ncBase = ((b * CKK + c) * HH + h) * WW + w0;
        const float4* src = (const float4*)(lds + c * SEG * 6);
        float4* dst = (float4*)(out + 6 * ncBase);
        #pragma unroll
        for (int i = tid; i < SEG * 6 / 4; i += 256)          // 384
            dst[i] = src[i];
    }
}

extern "C" void kernel_launch(void* const* d_in, const int* in_sizes, int n_in,
                              void* d_out, int out_size, void* d_ws, size_t ws_size,
                              hipStream_t stream) {
    const float* in = (const float*)d_in[0];
    float* out = (float*)d_out;
    ProjectBEV_kernel<<<NBLK, 256, 0, stream>>>(in, out);
}